// Round 3
// baseline (1431.995 us; speedup 1.0000x reference)
//
#include <hip/hip_runtime.h>
#include <hip/hip_bf16.h>

typedef unsigned short u16;
typedef unsigned int u32;
typedef __attribute__((ext_vector_type(8))) __bf16 bf16x8;
typedef __attribute__((ext_vector_type(4))) float f32x4;

#define NT 50000
#define NEDGE 1600000
#define NBKT 12500          // dst>>2 ; 4 rows per bucket ; 12500*4 == 50000
#define HBLK 128            // histogram blocks
#define EPB 12500           // edges per hist block (128*12500 == 1.6M)
#define GRID 256
#define NWV 15
#define TOTW (GRID * NWV)   // 3840 waves

__device__ __forceinline__ u16 f2bf(float f) {
  unsigned x = __float_as_uint(f);
  x += 0x7fffu + ((x >> 16) & 1u);
  return (u16)(x >> 16);
}

// element index into a [R][128] bf16 LDS tile, 16B-chunk XOR swizzle
__device__ __forceinline__ int swz(int row, int col) {
  return (row << 7) + (col ^ ((row & 7) << 3));
}

// tanh-form GELU
__device__ __forceinline__ float gelu(float v) {
  float t = v * (0.797884561f + 0.0356774081f * v * v);
  return v * __builtin_amdgcn_rcpf(1.0f + __expf(-2.0f * t));
}

__device__ __forceinline__ void atomAddF32(float* p, float v) {
#if defined(__has_builtin)
#if __has_builtin(__builtin_amdgcn_global_atomic_fadd_f32)
  __builtin_amdgcn_global_atomic_fadd_f32((__attribute__((address_space(1))) float*)p, v);
  return;
#endif
#endif
  atomicAdd(p, v);
}

// ---------------- prep kernels ----------------

__global__ void prep_w(const float* __restrict__ W1, const float* __restrict__ W2,
                       u16* __restrict__ wsw) {
  int t = blockIdx.x * 256 + threadIdx.x;   // 0..32767
  int m = t >> 14;
  int p = t & 16383;
  int row = p >> 7;
  int colq = p & 127;
  int k = colq ^ ((row & 7) << 3);
  const float* W = m ? W2 : W1;
  wsw[t] = f2bf(W[k * 128 + row]);          // W^T[n][k] = W[k][n]
}

__global__ void prep_h(const float* __restrict__ H, u16* __restrict__ Hb) {
  int t = blockIdx.x * 256 + threadIdx.x;   // 800000 threads, 8 elems each
  const float4* s = (const float4*)H + (long)t * 2;
  float4 a = s[0], c = s[1];
  int4 pk;
  pk.x = f2bf(a.x) | ((int)f2bf(a.y) << 16);
  pk.y = f2bf(a.z) | ((int)f2bf(a.w) << 16);
  pk.z = f2bf(c.x) | ((int)f2bf(c.y) << 16);
  pk.w = f2bf(c.z) | ((int)f2bf(c.w) << 16);
  ((int4*)Hb)[t] = pk;
}

__global__ void copy_h(const float4* __restrict__ H, float4* __restrict__ out) {
  int t = blockIdx.x * 256 + threadIdx.x;
  out[t] = H[t];
}

// ---------------- atomic-free bucket sort by dst ----------------

__global__ void hist_k(const int* __restrict__ ei, u32* __restrict__ off) {
  __shared__ u32 hcnt[NBKT];
  int tid = threadIdx.x;
  for (int i = tid; i < NBKT; i += 256) hcnt[i] = 0;
  __syncthreads();
  int e0 = blockIdx.x * EPB;
  for (int i = tid; i < EPB; i += 256) {
    int d = ei[NEDGE + e0 + i];
    atomicAdd(&hcnt[d >> 2], 1u);
  }
  __syncthreads();
  for (int i = tid; i < NBKT; i += 256) off[i * HBLK + blockIdx.x] = hcnt[i];
}

__global__ void scan_rows(u32* __restrict__ off, u32* __restrict__ base) {
  int b = blockIdx.x * 256 + threadIdx.x;
  if (b >= NBKT) return;
  u32 run = 0;
  for (int h = 0; h < HBLK; ++h) {
    u32 c = off[b * HBLK + h];
    off[b * HBLK + h] = run;
    run += c;
  }
  base[b] = run;   // per-bucket total
}

__global__ void scan_base(u32* __restrict__ base) {   // <<<1,1024>>>
  __shared__ u32 ls[1024];
  int tid = threadIdx.x;
  u32 v[13];
  u32 s = 0;
#pragma unroll
  for (int j = 0; j < 13; ++j) {
    int b = tid * 13 + j;
    v[j] = (b < NBKT) ? base[b] : 0u;
    s += v[j];
  }
  ls[tid] = s;
  __syncthreads();
  for (int o = 1; o < 1024; o <<= 1) {
    u32 t = (tid >= o) ? ls[tid - o] : 0u;
    __syncthreads();
    ls[tid] += t;
    __syncthreads();
  }
  u32 run = ls[tid] - s;   // exclusive
#pragma unroll
  for (int j = 0; j < 13; ++j) {
    int b = tid * 13 + j;
    if (b < NBKT) {
      u32 c = v[j];
      base[b] = run;
      run += c;
    }
  }
  if (tid == 1023) base[NBKT] = NEDGE;
}

__global__ void add_base(u32* __restrict__ off, const u32* __restrict__ base) {
  int t = blockIdx.x * 256 + threadIdx.x;   // < NBKT*HBLK = 1.6M
  off[t] += base[t >> 7];
}

__global__ void scatter_k(const int* __restrict__ ei, const u32* __restrict__ off,
                          u32* __restrict__ sorted, u32* __restrict__ perm) {
  __shared__ u32 so[NBKT];
  int tid = threadIdx.x;
  int h = blockIdx.x;
  for (int i = tid; i < NBKT; i += 256) so[i] = off[i * HBLK + h];
  __syncthreads();
  int e0 = h * EPB;
  for (int i = tid; i < EPB; i += 256) {
    int e = e0 + i;
    int d = ei[NEDGE + e];
    int s = ei[e];
    u32 p = atomicAdd(&so[d >> 2], 1u);
    sorted[p] = ((u32)s << 16) | (u32)d;
    perm[p] = (u32)e;
  }
}

// ---------------- message kernel (sorted, atomic-free output) ----------------

__launch_bounds__(960, 4)
__global__ void msg_sorted(const u16* __restrict__ Hb,
                           const float* __restrict__ ea,
                           const float* __restrict__ W1,
                           const float* __restrict__ b1,
                           const float* __restrict__ b2,
                           const u16* __restrict__ wsw,
                           const u32* __restrict__ base,
                           const u32* __restrict__ sorted,
                           const u32* __restrict__ perm,
                           float* __restrict__ out) {
  __shared__ __align__(16) u16 lw1[16384];
  __shared__ __align__(16) u16 lw2[16384];
  __shared__ __align__(16) u16 lh[NWV * 2048];     // 15 x (16x128 bf16)
  __shared__ __align__(16) float lacc[NWV * 544];  // 15 x (4 rows x 136 f32, padded)
  __shared__ __align__(16) float lep[5][128];

  const int tid = threadIdx.x;

  {  // stage pre-swizzled weights
    const int4* g = (const int4*)wsw;
    int4* d1 = (int4*)lw1;
    int4* d2 = (int4*)lw2;
    for (int c = tid; c < 2048; c += 960) { d1[c] = g[c]; d2[c] = g[2048 + c]; }
  }
  if (tid < 128) {
    lep[0][tid] = b1[tid];
    lep[1][tid] = W1[128 * 128 + tid];
    lep[2][tid] = W1[129 * 128 + tid];
    lep[3][tid] = W1[130 * 128 + tid];
    lep[4][tid] = b2[tid];
  }
  __syncthreads();   // only barrier

  const int wv = tid >> 6, lane = tid & 63;
  const int l15 = lane & 15, l4 = lane >> 4;
  u16* lhw = lh + wv * 2048;
  float* acc4 = lacc + wv * 544;

  for (int i = lane; i < 544; i += 64) acc4[i] = 0.f;

  const int gid = blockIdx.x * NWV + wv;
  const int bk0 = (int)(((long)gid * NBKT) / TOTW);
  const int bk1 = (int)(((long)(gid + 1) * NBKT) / TOTW);

  for (int bkt = bk0; bkt < bk1; ++bkt) {
    const int start = (int)base[bkt];
    const int cnt = (int)base[bkt + 1] - start;
    if (cnt == 0) continue;
    const int ntile = (cnt + 15) >> 4;

    for (int t = 0; t < ntile; ++t) {
      int i = t * 16 + l15;
      int idx = start + (i < cnt ? i : cnt - 1);
      u32 w = sorted[idx];
      u32 orig = perm[idx];
      int src = (int)(w >> 16);
      float ea0 = ea[orig * 3 + 0], ea1 = ea[orig * 3 + 1], ea2 = ea[orig * 3 + 2];

      const u16* hr = Hb + (long)src * 128;
      bf16x8 bfr[4];
#pragma unroll
      for (int ks = 0; ks < 4; ++ks)
        bfr[ks] = *(const bf16x8*)(hr + ks * 32 + l4 * 8);

      // ---- layer 1 (D[n][e]: e=l15, n=(l4,r)), GELU, write h tile ----
#pragma unroll
      for (int nt = 0; nt < 8; ++nt) {
        bf16x8 afr[4];
#pragma unroll
        for (int ks = 0; ks < 4; ++ks)
          afr[ks] = *(const bf16x8*)&lw1[swz(nt * 16 + l15, ks * 32 + l4 * 8)];
        f32x4 acc = (f32x4){0.f, 0.f, 0.f, 0.f};
#pragma unroll
        for (int ks = 0; ks < 4; ++ks)
          acc = __builtin_amdgcn_mfma_f32_16x16x32_bf16(afr[ks], bfr[ks], acc, 0, 0, 0);

        f32x4 b1v = *(const f32x4*)&lep[0][nt * 16 + l4 * 4];
        f32x4 w0v = *(const f32x4*)&lep[1][nt * 16 + l4 * 4];
        f32x4 w1v = *(const f32x4*)&lep[2][nt * 16 + l4 * 4];
        f32x4 w2v = *(const f32x4*)&lep[3][nt * 16 + l4 * 4];
        float hv[4];
#pragma unroll
        for (int r = 0; r < 4; ++r) {
          float v = acc[r] + b1v[r] + ea0 * w0v[r] + ea1 * w1v[r] + ea2 * w2v[r];
          hv[r] = gelu(v);
        }
        int2 hp;
        hp.x = f2bf(hv[0]) | ((int)f2bf(hv[1]) << 16);
        hp.y = f2bf(hv[2]) | ((int)f2bf(hv[3]) << 16);
        *(int2*)&lhw[swz(l15, nt * 16 + l4 * 4)] = hp;
      }

      asm volatile("" ::: "memory");

      // ---- layer 2 (D: e=(l4,r), n=l15) -> LDS accum (near atomics) ----
      bf16x8 ha[4];
#pragma unroll
      for (int ks = 0; ks < 4; ++ks)
        ha[ks] = *(const bf16x8*)&lhw[swz(l15, ks * 32 + l4 * 8)];

#pragma unroll
      for (int nt = 0; nt < 8; ++nt) {
        bf16x8 bfr2[4];
#pragma unroll
        for (int ks = 0; ks < 4; ++ks)
          bfr2[ks] = *(const bf16x8*)&lw2[swz(nt * 16 + l15, ks * 32 + l4 * 8)];
        float b2v = lep[4][nt * 16 + l15];
        f32x4 acc = (f32x4){0.f, 0.f, 0.f, 0.f};
#pragma unroll
        for (int ks = 0; ks < 4; ++ks)
          acc = __builtin_amdgcn_mfma_f32_16x16x32_bf16(ha[ks], bfr2[ks], acc, 0, 0, 0);
#pragma unroll
        for (int r = 0; r < 4; ++r) {
          int er = l4 * 4 + r;
          u32 wr = (u32)__shfl((int)w, er);
          if (t * 16 + er < cnt) {
            int dl = (int)(wr & 3u);
            atomicAdd(&acc4[dl * 136 + nt * 16 + l15], acc[r] + b2v);
          }
        }
      }
    }

    // ---- flush bucket: out rows owned exclusively by this wave ----
    {
      int row = lane >> 4, colb = l15 * 8;
      float4 v0 = *(const float4*)&acc4[row * 136 + colb];
      float4 v1 = *(const float4*)&acc4[row * 136 + colb + 4];
      float* g = out + ((long)bkt * 4 + row) * 128 + colb;
      float4 o0 = *(const float4*)g;
      float4 o1 = *(const float4*)(g + 4);
      o0.x += v0.x; o0.y += v0.y; o0.z += v0.z; o0.w += v0.w;
      o1.x += v1.x; o1.y += v1.y; o1.z += v1.z; o1.w += v1.w;
      *(float4*)g = o0;
      *(float4*)(g + 4) = o1;
      float4 z = (float4){0.f, 0.f, 0.f, 0.f};
      *(float4*)&acc4[row * 136 + colb] = z;
      *(float4*)&acc4[row * 136 + colb + 4] = z;
    }
  }
}

// ---------------- fallback (ws too small): unsorted + far atomics ----------------

template <int BF16H>
__launch_bounds__(960, 4)
__global__ void msg_atomic(const float* __restrict__ H,
                           const u16* __restrict__ Hb,
                           const int* __restrict__ ei,
                           const float* __restrict__ ea,
                           const float* __restrict__ W1,
                           const float* __restrict__ b1,
                           const float* __restrict__ b2,
                           const u16* __restrict__ wsw,
                           float* __restrict__ out) {
  __shared__ __align__(16) u16 lw1[16384];
  __shared__ __align__(16) u16 lw2[16384];
  __shared__ __align__(16) u16 lh[NWV * 2048];
  __shared__ __align__(16) float lep[5][128];

  const int tid = threadIdx.x;
  {
    const int4* g = (const int4*)wsw;
    int4* d1 = (int4*)lw1;
    int4* d2 = (int4*)lw2;
    for (int c = tid; c < 2048; c += 960) { d1[c] = g[c]; d2[c] = g[2048 + c]; }
  }
  if (tid < 128) {
    lep[0][tid] = b1[tid];
    lep[1][tid] = W1[128 * 128 + tid];
    lep[2][tid] = W1[129 * 128 + tid];
    lep[3][tid] = W1[130 * 128 + tid];
    lep[4][tid] = b2[tid];
  }
  __syncthreads();

  const int wv = tid >> 6, lane = tid & 63;
  const int l15 = lane & 15, l4 = lane >> 4;
  u16* lhw = lh + wv * 2048;
  const int gwid = blockIdx.x * NWV + wv;

  for (int g = gwid; g < NEDGE / 16; g += TOTW) {
    const int eb = g * 16;
    int src = ei[eb + l15];
    float ea0 = ea[(eb + l15) * 3 + 0], ea1 = ea[(eb + l15) * 3 + 1], ea2 = ea[(eb + l15) * 3 + 2];

    bf16x8 bfr[4];
    if (BF16H) {
      const u16* hr = Hb + (long)src * 128;
#pragma unroll
      for (int ks = 0; ks < 4; ++ks)
        bfr[ks] = *(const bf16x8*)(hr + ks * 32 + l4 * 8);
    } else {
      const float* hr = H + (long)src * 128;
#pragma unroll
      for (int ks = 0; ks < 4; ++ks) {
        float4 a = *(const float4*)(hr + ks * 32 + l4 * 8);
        float4 c = *(const float4*)(hr + ks * 32 + l4 * 8 + 4);
        int4 pk;
        pk.x = f2bf(a.x) | ((int)f2bf(a.y) << 16);
        pk.y = f2bf(a.z) | ((int)f2bf(a.w) << 16);
        pk.z = f2bf(c.x) | ((int)f2bf(c.y) << 16);
        pk.w = f2bf(c.z) | ((int)f2bf(c.w) << 16);
        bfr[ks] = *(bf16x8*)&pk;
      }
    }

#pragma unroll
    for (int nt = 0; nt < 8; ++nt) {
      bf16x8 afr[4];
#pragma unroll
      for (int ks = 0; ks < 4; ++ks)
        afr[ks] = *(const bf16x8*)&lw1[swz(nt * 16 + l15, ks * 32 + l4 * 8)];
      f32x4 acc = (f32x4){0.f, 0.f, 0.f, 0.f};
#pragma unroll
      for (int ks = 0; ks < 4; ++ks)
        acc = __builtin_amdgcn_mfma_f32_16x16x32_bf16(afr[ks], bfr[ks], acc, 0, 0, 0);
      f32x4 b1v = *(const f32x4*)&lep[0][nt * 16 + l4 * 4];
      f32x4 w0v = *(const f32x4*)&lep[1][nt * 16 + l4 * 4];
      f32x4 w1v = *(const f32x4*)&lep[2][nt * 16 + l4 * 4];
      f32x4 w2v = *(const f32x4*)&lep[3][nt * 16 + l4 * 4];
      float hv[4];
#pragma unroll
      for (int r = 0; r < 4; ++r) {
        float v = acc[r] + b1v[r] + ea0 * w0v[r] + ea1 * w1v[r] + ea2 * w2v[r];
        hv[r] = gelu(v);
      }
      int2 hp;
      hp.x = f2bf(hv[0]) | ((int)f2bf(hv[1]) << 16);
      hp.y = f2bf(hv[2]) | ((int)f2bf(hv[3]) << 16);
      *(int2*)&lhw[swz(l15, nt * 16 + l4 * 4)] = hp;
    }

    asm volatile("" ::: "memory");

    bf16x8 ha[4];
#pragma unroll
    for (int ks = 0; ks < 4; ++ks)
      ha[ks] = *(const bf16x8*)&lhw[swz(l15, ks * 32 + l4 * 8)];
    int drow[4];
#pragma unroll
    for (int r = 0; r < 4; ++r) drow[r] = ei[NEDGE + eb + l4 * 4 + r];

#pragma unroll
    for (int nt = 0; nt < 8; ++nt) {
      bf16x8 bfr2[4];
#pragma unroll
      for (int ks = 0; ks < 4; ++ks)
        bfr2[ks] = *(const bf16x8*)&lw2[swz(nt * 16 + l15, ks * 32 + l4 * 8)];
      float b2v = lep[4][nt * 16 + l15];
      f32x4 acc = (f32x4){0.f, 0.f, 0.f, 0.f};
#pragma unroll
      for (int ks = 0; ks < 4; ++ks)
        acc = __builtin_amdgcn_mfma_f32_16x16x32_bf16(ha[ks], bfr2[ks], acc, 0, 0, 0);
#pragma unroll
      for (int r = 0; r < 4; ++r)
        atomAddF32(out + (long)drow[r] * 128 + nt * 16 + l15, acc[r] + b2v);
    }
  }
}

__global__ void ln_rows(float* __restrict__ out, const float* __restrict__ gamma,
                        const float* __restrict__ beta) {
  int wave = threadIdx.x >> 6, lane = threadIdx.x & 63;
  int row = blockIdx.x * 4 + wave;
  float2 v = *(const float2*)(out + (long)row * 128 + lane * 2);
  float s = v.x + v.y;
#pragma unroll
  for (int off = 32; off; off >>= 1) s += __shfl_xor(s, off);
  float mu = s * (1.0f / 128.0f);
  float dx = v.x - mu, dy = v.y - mu;
  float q = dx * dx + dy * dy;
#pragma unroll
  for (int off = 32; off; off >>= 1) q += __shfl_xor(q, off);
  float rs = rsqrtf(q * (1.0f / 128.0f) + 1e-5f);
  float2 g = *(const float2*)(gamma + lane * 2);
  float2 b = *(const float2*)(beta + lane * 2);
  float2 o;
  o.x = dx * rs * g.x + b.x;
  o.y = dy * rs * g.y + b.y;
  *(float2*)(out + (long)row * 128 + lane * 2) = o;
}

extern "C" void kernel_launch(void* const* d_in, const int* in_sizes, int n_in,
                              void* d_out, int out_size, void* d_ws, size_t ws_size,
                              hipStream_t stream) {
  const float* H   = (const float*)d_in[0];
  const int* ei    = (const int*)d_in[1];
  const float* ea  = (const float*)d_in[2];
  const float* W1  = (const float*)d_in[3];
  const float* b1  = (const float*)d_in[4];
  const float* W2  = (const float*)d_in[5];
  const float* b2  = (const float*)d_in[6];
  const float* gam = (const float*)d_in[7];
  const float* bet = (const float*)d_in[8];
  float* out = (float*)d_out;

  char* ws = (char*)d_ws;
  u16* wsw = (u16*)ws;                                   //      65,536 B
  u16* Hb  = (u16*)(ws + 65536);                         //  12,800,000 B
  u32* off = (u32*)(ws + 12865536);                      //   6,400,000 B
  u32* bse = (u32*)(ws + 19265536);                      //      50,004 B
  u32* srt = (u32*)(ws + 19315540);                      //   6,400,000 B
  u32* prm = (u32*)(ws + 25715540);                      //   6,400,000 B
  const size_t NEED_FULL = 32115540;
  const size_t NEED_HB = 12865536;

  prep_w<<<128, 256, 0, stream>>>(W1, W2, wsw);
  copy_h<<<6250, 256, 0, stream>>>((const float4*)H, (float4*)out);

  if (ws_size >= NEED_FULL) {
    prep_h<<<3125, 256, 0, stream>>>(H, Hb);
    hist_k<<<HBLK, 256, 0, stream>>>(ei, off);
    scan_rows<<<49, 256, 0, stream>>>(off, bse);
    scan_base<<<1, 1024, 0, stream>>>(bse);
    add_base<<<6250, 256, 0, stream>>>(off, bse);
    scatter_k<<<HBLK, 256, 0, stream>>>(ei, off, srt, prm);
    msg_sorted<<<GRID, 960, 0, stream>>>(Hb, ea, W1, b1, b2, wsw, bse, srt, prm, out);
  } else if (ws_size >= NEED_HB) {
    prep_h<<<3125, 256, 0, stream>>>(H, Hb);
    msg_atomic<1><<<GRID, 960, 0, stream>>>(H, Hb, ei, ea, W1, b1, b2, wsw, out);
  } else {
    msg_atomic<0><<<GRID, 960, 0, stream>>>(H, Hb, ei, ea, W1, b1, b2, wsw, out);
  }

  ln_rows<<<12500, 256, 0, stream>>>(out, gam, bet);
}